// Round 1
// baseline (3470.770 us; speedup 1.0000x reference)
//
#include <hip/hip_runtime.h>

#define NT 512
#define DD 64
#define BB 8
#define NTHREADS 256

// ---------------- LDS layout (float offsets) ----------------
// Weights stored transposed: Wt[k][row] = W[row][k], row in [0, 3*dh)
#define WI0 0       // 64x96 = 6144
#define WH0 6144    // 32x96 = 3072
#define WI1 9216    // 32x48 = 1536
#define WH1 10752   // 16x48 = 768
#define WI2 11520   // 16x24 = 384
#define WH2 11904   //  8x24 = 192
#define WI3 12096   //  8x48 = 384
#define WH3 12480   // 16x48 = 768
#define WI4 13248   // 16x96 = 1536
#define WH4 14784   // 32x96 = 3072
#define OWT 17856   // 32x64 = 2048 (out_wT[k][d])
#define BI0 19904
#define BH0 20000
#define BI1 20096
#define BH1 20144
#define BI2 20192
#define BH2 20216
#define BI3 20240
#define BH3 20288
#define BI4 20336
#define BH4 20432
#define OB  20528   // 64
#define XBUF 21104  // moved after OB+64=20592; keep simple: XBUF at 20592
#undef XBUF
#define XBUF 20592  // 8x64 = 512
#define H0  21104   // 2 x 8 x 32 = 512
#define H1  21616   // 2 x 8 x 16 = 256
#define H2  21872   // 2 x 8 x 8  = 128
#define H3  22000   // 2 x 8 x 16 = 256
#define H4  22256   // 2 x 8 x 32 = 512
#define LDS_FLOATS 22768
#define LDS_BYTES (LDS_FLOATS * 4)
#define H_TOTAL (LDS_FLOATS - H0)   // 1664

__device__ __forceinline__ float sigf(float x) { return 1.0f / (1.0f + __expf(-x)); }
__device__ __forceinline__ float tanh_fast(float x) { return 2.0f / (1.0f + __expf(-2.0f * x)) - 1.0f; }

// One GRU cell evaluation for (bb, j): all 6 dot products + gates.
// Wti: [DIN][3*DH] transposed, Wth: [DH][3*DH] transposed.
template <int DIN, int DH>
__device__ __forceinline__ void gru_cell(int bb, int j,
    const float* Wti, const float* Wth,
    const float* bi, const float* bh,
    const float* xin,    // [BB][DIN]
    const float* hprev,  // [BB][DH]
    float* hnew)         // [BB][DH]
{
    constexpr int S = 3 * DH;
    float ir = bi[j], iz = bi[DH + j], inn = bi[2 * DH + j];
    const float* xp = xin + bb * DIN;
#pragma unroll
    for (int k = 0; k < DIN; ++k) {
        float xk = xp[k];
        const float* w = Wti + k * S;
        ir  += w[j] * xk;
        iz  += w[DH + j] * xk;
        inn += w[2 * DH + j] * xk;
    }
    float hr = bh[j], hz = bh[DH + j], hn = bh[2 * DH + j];
    const float* hp = hprev + bb * DH;
#pragma unroll
    for (int k = 0; k < DH; ++k) {
        float hk = hp[k];
        const float* w = Wth + k * S;
        hr += w[j] * hk;
        hz += w[DH + j] * hk;
        hn += w[2 * DH + j] * hk;
    }
    float r = sigf(ir + hr);
    float z = sigf(iz + hz);
    float n = tanh_fast(inn + r * hn);
    hnew[bb * DH + j] = (1.0f - z) * n + z * hp[j];
}

__device__ __forceinline__ void copy_wT(const float* g, float* dst, int rows, int cols_log2, int tid) {
    int cols = 1 << cols_log2;
    int n = rows << cols_log2;
    for (int i = tid; i < n; i += NTHREADS) {
        int r = i >> cols_log2;
        int k = i & (cols - 1);
        dst[k * rows + r] = g[i];
    }
}
__device__ __forceinline__ void copy_v(const float* g, float* dst, int n, int tid) {
    for (int i = tid; i < n; i += NTHREADS) dst[i] = g[i];
}

__global__ __launch_bounds__(NTHREADS)
void gru_fused(const float* __restrict__ X, const float* __restrict__ M, const float* __restrict__ L,
               const float* __restrict__ wih0, const float* __restrict__ whh0, const float* __restrict__ bih0, const float* __restrict__ bhh0,
               const float* __restrict__ wih1, const float* __restrict__ whh1, const float* __restrict__ bih1, const float* __restrict__ bhh1,
               const float* __restrict__ wih2, const float* __restrict__ whh2, const float* __restrict__ bih2, const float* __restrict__ bhh2,
               const float* __restrict__ wih3, const float* __restrict__ whh3, const float* __restrict__ bih3, const float* __restrict__ bhh3,
               const float* __restrict__ wih4, const float* __restrict__ whh4, const float* __restrict__ bih4, const float* __restrict__ bhh4,
               const float* __restrict__ out_w, const float* __restrict__ out_b,
               float* __restrict__ out)
{
    extern __shared__ float smem[];
    const int tid = threadIdx.x;

    // Stage all weights (transposed) + biases into LDS once.
    copy_wT(wih0, smem + WI0, 96, 6, tid);
    copy_wT(whh0, smem + WH0, 96, 5, tid);
    copy_wT(wih1, smem + WI1, 48, 5, tid);
    copy_wT(whh1, smem + WH1, 48, 4, tid);
    copy_wT(wih2, smem + WI2, 24, 4, tid);
    copy_wT(whh2, smem + WH2, 24, 3, tid);
    copy_wT(wih3, smem + WI3, 48, 3, tid);
    copy_wT(whh3, smem + WH3, 48, 4, tid);
    copy_wT(wih4, smem + WI4, 96, 4, tid);
    copy_wT(whh4, smem + WH4, 96, 5, tid);
    copy_wT(out_w, smem + OWT, 64, 5, tid);
    copy_v(bih0, smem + BI0, 96, tid);
    copy_v(bhh0, smem + BH0, 96, tid);
    copy_v(bih1, smem + BI1, 48, tid);
    copy_v(bhh1, smem + BH1, 48, tid);
    copy_v(bih2, smem + BI2, 24, tid);
    copy_v(bhh2, smem + BH2, 24, tid);
    copy_v(bih3, smem + BI3, 48, tid);
    copy_v(bhh3, smem + BH3, 48, tid);
    copy_v(bih4, smem + BI4, 96, tid);
    copy_v(bhh4, smem + BH4, 96, tid);
    copy_v(out_b, smem + OB, 64, tid);
    // Zero hidden-state double buffers.
    for (int i = tid; i < H_TOTAL; i += NTHREADS) smem[H0 + i] = 0.0f;
    __syncthreads();

    const int b0 = blockIdx.x * BB;

    // Prefetch registers for x (2 elements per thread: f = tid, tid+256).
    float rx[2], rm[2], rl[2];
#pragma unroll
    for (int u = 0; u < 2; ++u) {
        int f = tid + u * NTHREADS;
        int bb = f >> 6, d = f & 63;
        size_t g = ((size_t)(b0 + bb) * NT + 0) * DD + d;
        rx[u] = X[g]; rm[u] = M[g]; rl[u] = L[g];
    }

    for (int t = 0; t < NT; ++t) {
        const int p = t & 1, q = p ^ 1;

        // Stage A: write imputed x for this timestep, prefetch next.
#pragma unroll
        for (int u = 0; u < 2; ++u) {
            int f = tid + u * NTHREADS;
            smem[XBUF + f] = rx[u] * rm[u] + rl[u] * (1.0f - rm[u]);
        }
        if (t + 1 < NT) {
#pragma unroll
            for (int u = 0; u < 2; ++u) {
                int f = tid + u * NTHREADS;
                int bb = f >> 6, d = f & 63;
                size_t g = ((size_t)(b0 + bb) * NT + (t + 1)) * DD + d;
                rx[u] = X[g]; rm[u] = M[g]; rl[u] = L[g];
            }
        }
        __syncthreads();

        // Layer 0: din=64, dh=32 -> 8*32 = 256 threads
        gru_cell<64, 32>(tid >> 5, tid & 31, smem + WI0, smem + WH0, smem + BI0, smem + BH0,
                         smem + XBUF, smem + H0 + p * 256, smem + H0 + q * 256);
        __syncthreads();

        // Layer 1: din=32, dh=16 -> 128 threads
        if (tid < 128)
            gru_cell<32, 16>(tid >> 4, tid & 15, smem + WI1, smem + WH1, smem + BI1, smem + BH1,
                             smem + H0 + q * 256, smem + H1 + p * 128, smem + H1 + q * 128);
        __syncthreads();

        // Layer 2: din=16, dh=8 -> 64 threads
        if (tid < 64)
            gru_cell<16, 8>(tid >> 3, tid & 7, smem + WI2, smem + WH2, smem + BI2, smem + BH2,
                            smem + H1 + q * 128, smem + H2 + p * 64, smem + H2 + q * 64);
        __syncthreads();

        // Layer 3: din=8, dh=16 -> 128 threads
        if (tid < 128)
            gru_cell<8, 16>(tid >> 4, tid & 15, smem + WI3, smem + WH3, smem + BI3, smem + BH3,
                            smem + H2 + q * 64, smem + H3 + p * 128, smem + H3 + q * 128);
        __syncthreads();

        // Layer 4: din=16, dh=32 -> 256 threads
        gru_cell<16, 32>(tid >> 5, tid & 31, smem + WI4, smem + WH4, smem + BI4, smem + BH4,
                         smem + H3 + q * 128, smem + H4 + p * 256, smem + H4 + q * 256);
        __syncthreads();

        // Output projection: h4_new[bb][32] @ out_w.T -> out[bb][t][64]
        for (int o = tid; o < BB * DD; o += NTHREADS) {
            int bb = o >> 6, d = o & 63;
            float acc = smem[OB + d];
            const float* hp = smem + H4 + q * 256 + bb * 32;
#pragma unroll
            for (int k = 0; k < 32; ++k) acc += smem[OWT + k * 64 + d] * hp[k];
            out[((size_t)(b0 + bb) * NT + t) * DD + d] = acc;
        }
        // No barrier needed here: next iteration's bar1 separates G(t) from B(t+1).
    }
}

extern "C" void kernel_launch(void* const* d_in, const int* in_sizes, int n_in,
                              void* d_out, int out_size, void* d_ws, size_t ws_size,
                              hipStream_t stream)
{
    const float* X  = (const float*)d_in[0];
    const float* M  = (const float*)d_in[1];
    const float* L  = (const float*)d_in[2];
    const float* w[20];
    for (int i = 0; i < 20; ++i) w[i] = (const float*)d_in[3 + i];
    const float* ow = (const float*)d_in[23];
    const float* ob = (const float*)d_in[24];
    float* out = (float*)d_out;

    // 91 KB dynamic LDS > 64 KB default cap -> raise the limit (gfx950 allows 160 KiB/WG).
    hipFuncSetAttribute((const void*)gru_fused, hipFuncAttributeMaxDynamicSharedMemorySize, LDS_BYTES);

    gru_fused<<<dim3(2048 / BB), dim3(NTHREADS), LDS_BYTES, stream>>>(
        X, M, L,
        w[0], w[1], w[2], w[3],
        w[4], w[5], w[6], w[7],
        w[8], w[9], w[10], w[11],
        w[12], w[13], w[14], w[15],
        w[16], w[17], w[18], w[19],
        ow, ob, out);
}

// Round 2
// 2093.963 us; speedup vs baseline: 1.6575x; 1.6575x over previous
//
#include <hip/hip_runtime.h>

#define NT 512
#define DD 64
#define BB 8
#define NTH 512
#define GST 320
#define GTOFF 2688
#define NSTEP 517   // 512 + 5 pipeline stages

// xbuf float offsets: ping-pong activation buffers [2][BB][width]
#define XB0 0      // [2][8][64] input x  (imputed)
#define XB1 1024   // [2][8][32] h0
#define XB2 1536   // [2][8][16] h1
#define XB3 1792   // [2][8][8]  h2
#define XB4 1920   // [2][8][16] h3
#define XB5 2176   // [2][8][32] h4
#define XTOT (GTOFF + BB*GST)  // 2688 + 2560 = 5248 floats = 21 KB

__device__ __forceinline__ float sigf(float x){ return 1.0f/(1.0f+__expf(-x)); }
__device__ __forceinline__ float tanhf2(float x){ return 2.0f/(1.0f+__expf(-2.0f*x)) - 1.0f; }

template<int DIN,int DH>
__device__ __forceinline__ void load_row(const float* __restrict__ wih, const float* __restrict__ whh,
    const float* __restrict__ bih, const float* __restrict__ bhh, int r,
    float (&wi)[64], float (&wh)[32], float& bi_, float& bh_)
{
#pragma unroll
  for (int k=0;k<DIN;k+=4){
    float4 v = *(const float4*)(wih + (size_t)r*DIN + k);
    wi[k]=v.x; wi[k+1]=v.y; wi[k+2]=v.z; wi[k+3]=v.w;
  }
#pragma unroll
  for (int k=0;k<DH;k+=4){
    float4 v = *(const float4*)(whh + (size_t)r*DH + k);
    wh[k]=v.x; wh[k+1]=v.y; wh[k+2]=v.z; wh[k+3]=v.w;
  }
  bi_ = bih[r]; bh_ = bhh[r];
}

// One gate-row dot product over all BB batch elements. xb/hb are LDS bases for
// this step's read parity. All LDS reads are wave-broadcast b128 (conflict-free).
template<int DIN,int DH>
__device__ __forceinline__ void dot_phase(
    const float* __restrict__ xb, const float* __restrict__ hb,
    const float (&wi)[64], const float (&wh)[32],
    float bi_, float bh_, bool is_n, float* __restrict__ gtw,
    float (&ai)[BB], float (&ah)[BB])
{
#pragma unroll
  for (int bb=0; bb<BB; ++bb) {
    const float* xp = xb + bb*DIN;
    float a = bi_;
#pragma unroll
    for (int k=0;k<DIN;k+=4){
      float4 x4 = *(const float4*)(xp + k);
      a = fmaf(wi[k],x4.x,a); a = fmaf(wi[k+1],x4.y,a);
      a = fmaf(wi[k+2],x4.z,a); a = fmaf(wi[k+3],x4.w,a);
    }
    const float* hp = hb + bb*DH;
    float h = bh_;
#pragma unroll
    for (int k=0;k<DH;k+=4){
      float4 h4 = *(const float4*)(hp + k);
      h = fmaf(wh[k],h4.x,h); h = fmaf(wh[k+1],h4.y,h);
      h = fmaf(wh[k+2],h4.z,h); h = fmaf(wh[k+3],h4.w,h);
    }
    if (is_n) { ai[bb]=a; ah[bb]=h; }          // n-gate keeps i/h sums separate
    else      gtw[bb*GST] = sigf(a+h);          // r,z gates publish sigmoid
  }
}

// n-gate threads: combine with r,z read from gate buffer, write new h.
template<int DH>
__device__ __forceinline__ void comb_phase(
    const float* __restrict__ gtr, const float* __restrict__ gtz,
    const float* __restrict__ hprev, float* __restrict__ hout, int j,
    const float (&ai)[BB], const float (&ah)[BB])
{
#pragma unroll
  for (int bb=0; bb<BB; ++bb) {
    float rr = gtr[bb*GST], zz = gtz[bb*GST];
    float hp = hprev[bb*DH + j];
    float n  = tanhf2(ai[bb] + rr*ah[bb]);
    hout[bb*DH + j] = (1.0f-zz)*n + zz*hp;
  }
}

__global__ __launch_bounds__(NTH)
void gru_pipe(const float* __restrict__ X, const float* __restrict__ M, const float* __restrict__ L,
              const float* __restrict__ wih0, const float* __restrict__ whh0, const float* __restrict__ bih0, const float* __restrict__ bhh0,
              const float* __restrict__ wih1, const float* __restrict__ whh1, const float* __restrict__ bih1, const float* __restrict__ bhh1,
              const float* __restrict__ wih2, const float* __restrict__ whh2, const float* __restrict__ bih2, const float* __restrict__ bhh2,
              const float* __restrict__ wih3, const float* __restrict__ whh3, const float* __restrict__ bih3, const float* __restrict__ bhh3,
              const float* __restrict__ wih4, const float* __restrict__ whh4, const float* __restrict__ bih4, const float* __restrict__ bhh4,
              const float* __restrict__ out_w, const float* __restrict__ out_b,
              float* __restrict__ out)
{
  __shared__ __align__(16) float xbuf[XTOT];
  const int tid = threadIdx.x;
  const int w = tid >> 6, lane = tid & 63;
  const int b0 = blockIdx.x * BB;

  float wi[64], wh[32], bi_=0.f, bh_=0.f, ai[BB], ah[BB];

  // Wave roles (pairs (w, w+4) share a SIMD -> balance FMA load):
  // w0: L0 rows 0..63 (r,z) | w4: L2 rows 0..23
  // w1: L0 rows 64..95 (n)  | w5: L3 rows 0..47
  // w2: L1 rows 0..47       | w6: L4 rows 0..47 (r,z)
  // w3: L4 rows 48..95      | w7: OUT d 0..63
  int r = 0; bool act = false; int goff = 0, dh = 1;
  switch (w) {
    case 0: r = lane;    act = true;      goff = 0;   dh = 32; break;
    case 1: r = 64+lane; act = lane<32;   goff = 0;   dh = 32; break;
    case 2: r = lane;    act = lane<48;   goff = 96;  dh = 16; break;
    case 3: r = 48+lane; act = lane<48;   goff = 216; dh = 32; break;
    case 4: r = lane;    act = lane<24;   goff = 144; dh = 8;  break;
    case 5: r = lane;    act = lane<48;   goff = 168; dh = 16; break;
    case 6: r = lane;    act = lane<48;   goff = 216; dh = 32; break;
    case 7: r = lane;    act = true;      goff = 0;   dh = 1;  break;
  }
  const int rc = act ? r : 0;

  if (w<=1)            load_row<64,32>(wih0,whh0,bih0,bhh0, rc, wi,wh,bi_,bh_);
  else if (w==2)       load_row<32,16>(wih1,whh1,bih1,bhh1, rc, wi,wh,bi_,bh_);
  else if (w==3||w==6) load_row<16,32>(wih4,whh4,bih4,bhh4, rc, wi,wh,bi_,bh_);
  else if (w==4)       load_row<16, 8>(wih2,whh2,bih2,bhh2, rc, wi,wh,bi_,bh_);
  else if (w==5)       load_row< 8,16>(wih3,whh3,bih3,bhh3, rc, wi,wh,bi_,bh_);
  else {
#pragma unroll
    for (int k=0;k<32;k+=4){
      float4 v = *(const float4*)(out_w + lane*32 + k);
      wi[k]=v.x; wi[k+1]=v.y; wi[k+2]=v.z; wi[k+3]=v.w;
    }
    bi_ = out_b[lane];
  }

  const bool is_n = act && (w!=7) && (r >= 2*dh);
  const int  jj   = is_n ? (r - 2*dh) : 0;
  float*       gtw = &xbuf[GTOFF + goff + rc];
  const float* gtr = &xbuf[GTOFF + goff + jj];
  const float* gtz = &xbuf[GTOFF + goff + dh + jj];

  // zero activation ping-pong buffers (h init = 0)
  for (int i = tid; i < GTOFF; i += NTH) xbuf[i] = 0.f;

  // preload x(t=0), write imputed into XB0 parity-1 (read at s=0), preload x(1)
  const size_t gbase = ((size_t)(b0 + (tid>>6)))*NT*DD + (tid&63);
  float rx = X[gbase], rm = M[gbase], rl = L[gbase];
  xbuf[XB0 + 512 + tid] = rx*rm + rl*(1.0f-rm);
  rx = X[gbase+DD]; rm = M[gbase+DD]; rl = L[gbase+DD];
  __syncthreads();

  for (int s = 0; s < NSTEP; ++s) {
    const int par = s & 1, rp = par ^ 1;

    // prefetch x(s+2) (consumed end of next step; full-step latency cover)
    float nx=0.f, nm=0.f, nl=0.f;
    if (s <= 509) {
      size_t g = gbase + (size_t)(s+2)*DD;
      nx = X[g]; nm = M[g]; nl = L[g];
    }

    // ---------------- phase 1: dot products / output projection ----------------
    if (w<=1) {
      if (s<=511 && act)
        dot_phase<64,32>(&xbuf[XB0+rp*512], &xbuf[XB1+rp*256], wi,wh,bi_,bh_, (w==1), gtw, ai,ah);
    } else if (w==2) {
      if (s>=1 && s<=512 && act)
        dot_phase<32,16>(&xbuf[XB1+rp*256], &xbuf[XB2+rp*128], wi,wh,bi_,bh_, is_n, gtw, ai,ah);
    } else if (w==3||w==6) {
      if (s>=4 && s<=515 && act)
        dot_phase<16,32>(&xbuf[XB4+rp*128], &xbuf[XB5+rp*256], wi,wh,bi_,bh_, is_n, gtw, ai,ah);
    } else if (w==4) {
      if (s>=2 && s<=513 && act)
        dot_phase<16, 8>(&xbuf[XB2+rp*128], &xbuf[XB3+rp*64],  wi,wh,bi_,bh_, is_n, gtw, ai,ah);
    } else if (w==5) {
      if (s>=3 && s<=514 && act)
        dot_phase< 8,16>(&xbuf[XB3+rp*64],  &xbuf[XB4+rp*128], wi,wh,bi_,bh_, is_n, gtw, ai,ah);
    } else { // w==7: output projection of h4(t), t = s-5
      if (s>=5) {
        const int t = s-5;
        const float* hb = &xbuf[XB5+rp*256];
#pragma unroll
        for (int bb=0;bb<BB;++bb){
          float a2 = bi_;
          const float* hp = hb + bb*32;
#pragma unroll
          for (int k=0;k<32;k+=4){
            float4 h4 = *(const float4*)(hp+k);
            a2 = fmaf(wi[k],h4.x,a2); a2 = fmaf(wi[k+1],h4.y,a2);
            a2 = fmaf(wi[k+2],h4.z,a2); a2 = fmaf(wi[k+3],h4.w,a2);
          }
          out[((size_t)(b0+bb)*NT + t)*DD + lane] = a2;
        }
      }
    }
    __syncthreads();

    // ---------------- phase 2: gate combine -> new h; impute next x ----------------
    if (w==1) {
      if (s<=511 && is_n)
        comb_phase<32>(gtr,gtz, &xbuf[XB1+rp*256], &xbuf[XB1+par*256], jj, ai,ah);
    } else if (w==2) {
      if (s>=1 && s<=512 && is_n)
        comb_phase<16>(gtr,gtz, &xbuf[XB2+rp*128], &xbuf[XB2+par*128], jj, ai,ah);
    } else if (w==3) {
      if (s>=4 && s<=515 && is_n)
        comb_phase<32>(gtr,gtz, &xbuf[XB5+rp*256], &xbuf[XB5+par*256], jj, ai,ah);
    } else if (w==4) {
      if (s>=2 && s<=513 && is_n)
        comb_phase< 8>(gtr,gtz, &xbuf[XB3+rp*64],  &xbuf[XB3+par*64],  jj, ai,ah);
    } else if (w==5) {
      if (s>=3 && s<=514 && is_n)
        comb_phase<16>(gtr,gtz, &xbuf[XB4+rp*128], &xbuf[XB4+par*128], jj, ai,ah);
    }
    // imputed x(s+1) into XB0[par] (read at step s+1)
    if (s <= 510) xbuf[XB0 + par*512 + tid] = rx*rm + rl*(1.0f-rm);
    rx = nx; rm = nm; rl = nl;
    __syncthreads();
  }
}

extern "C" void kernel_launch(void* const* d_in, const int* in_sizes, int n_in,
                              void* d_out, int out_size, void* d_ws, size_t ws_size,
                              hipStream_t stream)
{
  const float* X  = (const float*)d_in[0];
  const float* M  = (const float*)d_in[1];
  const float* L  = (const float*)d_in[2];
  const float* wp[20];
  for (int i = 0; i < 20; ++i) wp[i] = (const float*)d_in[3 + i];
  const float* ow = (const float*)d_in[23];
  const float* ob = (const float*)d_in[24];
  float* out = (float*)d_out;

  gru_pipe<<<dim3(2048 / BB), dim3(NTH), 0, stream>>>(
      X, M, L,
      wp[0], wp[1], wp[2], wp[3],
      wp[4], wp[5], wp[6], wp[7],
      wp[8], wp[9], wp[10], wp[11],
      wp[12], wp[13], wp[14], wp[15],
      wp[16], wp[17], wp[18], wp[19],
      ow, ob, out);
}

// Round 3
// 990.658 us; speedup vs baseline: 3.5035x; 2.1137x over previous
//
#include <hip/hip_runtime.h>

typedef short s16x8 __attribute__((ext_vector_type(8)));
typedef short s16x4 __attribute__((ext_vector_type(4)));
typedef float f32x4 __attribute__((ext_vector_type(4)));
typedef unsigned int u32;
typedef unsigned short u16;

#define NT 512
#define DD 64
#define BB 8
#define NTH 512
#define NSTEP 517   // 512 + 5 pipeline stages

// LDS fragment arena: chunk = [4 kb][2 hi/lo][16 bb][8 e] = 1024 u16 (one K=32 B-panel)
#define CHUNK 1024
#define PSTRIDE (7*CHUNK)   // per parity: XIN(2 chunks) + H0..H4 (1 each)
#define XIN0 0
#define H0C (2*CHUNK)
#define H1C (3*CHUNK)
#define H2C (4*CHUNK)
#define H3C (5*CHUNK)
#define H4C (6*CHUNK)
#define FRTOT (2*PSTRIDE)   // 14336 u16 = 28 KB

#define MFMA16(A,B,C) __builtin_amdgcn_mfma_f32_16x16x32_bf16(A,B,C,0,0,0)

__device__ __forceinline__ float sigf(float x){ return 1.0f/(1.0f+__expf(-x)); }
__device__ __forceinline__ float tanhf2(float x){ return 2.0f/(1.0f+__expf(-2.0f*x)) - 1.0f; }

__device__ __forceinline__ u16 f2bf(float f) {
  u32 u = __builtin_bit_cast(u32, f);
  return (u16)((u + 0x7fffu + ((u >> 16) & 1u)) >> 16);
}
__device__ __forceinline__ float bf2f(u16 h) {
  u32 u = ((u32)h) << 16;
  return __builtin_bit_cast(float, u);
}

// A-fragment: lane holds A[row0 + (lane&15)][kbase + (lane>>4)*8 + e], zero-padded.
__device__ __forceinline__ void load_wfrag(const float* __restrict__ W, int row0, int nrow, int din,
                                           int kbase, int lane, s16x8& hi, s16x8& lo)
{
  const int m = lane & 15, kb = lane >> 4;
#pragma unroll
  for (int e = 0; e < 8; ++e) {
    int k = kbase + kb*8 + e;
    float v = (m < nrow && k < din) ? W[(size_t)(row0 + m)*din + k] : 0.0f;
    u16 h = f2bf(v);
    hi[e] = (short)h;
    lo[e] = (short)f2bf(v - bf2f(h));
  }
}

// B-fragment read: lane reads B[k=(lane>>4)*8+e][col=lane&15] (hi at +0, lo at +128)
__device__ __forceinline__ void read_b(const u16* base, int lane, s16x8& hi, s16x8& lo)
{
  const int off = ((lane >> 4) << 8) + ((lane & 15) << 3);
  hi = *(const s16x8*)(base + off);
  lo = *(const s16x8*)(base + off + 128);
}

// imputed-x write into XIN chunk buffers (bb = w, d = lane), hi/lo split
__device__ __forceinline__ void write_x(u16* FRu, int par, int w, int lane, float v)
{
  const int d = lane;
  const int chunk = d >> 5, kb = (d >> 3) & 3, e = d & 7;
  u16 h = f2bf(v);
  u16 l2 = f2bf(v - bf2f(h));
  u16* p = FRu + par*PSTRIDE + XIN0 + chunk*CHUNK + kb*256 + w*8 + e;
  p[0] = h; p[128] = l2;
}

template<int DIN, int DH, int NXC>
__device__ __forceinline__ void wave_gru(
    const float* __restrict__ Wih, const float* __restrict__ Whh,
    const float* __restrict__ bih, const float* __restrict__ bhh,
    int jbase, int xc, int hc, int s0, int s1,
    u16* FRu, float* OST,
    const float* __restrict__ X, const float* __restrict__ Mm, const float* __restrict__ Ll,
    float* __restrict__ out, int b0, int w, int lane)
{
  const int nrow = (DH - jbase) < 16 ? (DH - jbase) : 16;
  // weights: 3 gates x (NXC x-chunks + 1 h-chunk), hi/lo
  s16x8 Axh[3][NXC], Axl[3][NXC], Ahh[3], Ahl[3];
#pragma unroll
  for (int g = 0; g < 3; ++g) {
#pragma unroll
    for (int c = 0; c < NXC; ++c)
      load_wfrag(Wih, g*DH + jbase, nrow, DIN, c*32, lane, Axh[g][c], Axl[g][c]);
    load_wfrag(Whh, g*DH + jbase, nrow, DH, 0, lane, Ahh[g], Ahl[g]);
  }
  // bias -> accumulator init (r,z get bi+bh; n keeps i/h parts separate)
  f32x4 cR, cZ, cNi, cNh;
  {
    const int q = lane >> 4;
#pragma unroll
    for (int i = 0; i < 4; ++i) {
      int lr = q*4 + i;
      int j = jbase + lr;
      bool jr = lr < nrow;
      cR[i]  = jr ? bih[j] + bhh[j] : 0.f;
      cZ[i]  = jr ? bih[DH+j] + bhh[DH+j] : 0.f;
      cNi[i] = jr ? bih[2*DH+j] : 0.f;
      cNh[i] = jr ? bhh[2*DH+j] : 0.f;
    }
  }
  float hprev[4] = {0.f, 0.f, 0.f, 0.f};

  const size_t gbase = ((size_t)(b0 + w))*((size_t)NT*DD) + lane;
  float rx = X[gbase], rm = Mm[gbase], rl = Ll[gbase];
  write_x(FRu, 1, w, lane, rx*rm + rl*(1.0f - rm));   // x(0) -> parity 1
  rx = X[gbase + DD]; rm = Mm[gbase + DD]; rl = Ll[gbase + DD];
  __syncthreads();

  for (int s = 0; s < NSTEP; ++s) {
    const int par = s & 1, rp = par ^ 1;
    float nx = 0.f, nm = 0.f, nl = 0.f;
    if (s <= 509) {
      size_t g = gbase + (size_t)(s+2)*DD;
      nx = X[g]; nm = Mm[g]; nl = Ll[g];
    }
    f32x4 aR = cR, aZ = cZ, aNi = cNi, aNh = cNh;
    const bool run = (s >= s0) && (s <= s1);
    if (run) {
      const u16* RB = FRu + rp*PSTRIDE;
      s16x8 bh_, bl_;
#pragma unroll
      for (int c = 0; c < NXC; ++c) {
        read_b(RB + xc + c*CHUNK, lane, bh_, bl_);
        aR  = MFMA16(Axh[0][c], bh_, aR);  aR  = MFMA16(Axh[0][c], bl_, aR);  aR  = MFMA16(Axl[0][c], bh_, aR);
        aZ  = MFMA16(Axh[1][c], bh_, aZ);  aZ  = MFMA16(Axh[1][c], bl_, aZ);  aZ  = MFMA16(Axl[1][c], bh_, aZ);
        aNi = MFMA16(Axh[2][c], bh_, aNi); aNi = MFMA16(Axh[2][c], bl_, aNi); aNi = MFMA16(Axl[2][c], bh_, aNi);
      }
      read_b(RB + hc, lane, bh_, bl_);
      aR  = MFMA16(Ahh[0], bh_, aR);  aR  = MFMA16(Ahh[0], bl_, aR);  aR  = MFMA16(Ahl[0], bh_, aR);
      aZ  = MFMA16(Ahh[1], bh_, aZ);  aZ  = MFMA16(Ahh[1], bl_, aZ);  aZ  = MFMA16(Ahl[1], bh_, aZ);
      aNh = MFMA16(Ahh[2], bh_, aNh); aNh = MFMA16(Ahh[2], bl_, aNh); aNh = MFMA16(Ahl[2], bh_, aNh);
    }
    __syncthreads();   // barrier A: outstage ready; frag reads done

    if (run) {
      // in-register gate combine: lane owns (bb = lane&15, j = jbase + (lane>>4)*4 + i)
      const int bb = lane & 15, q = lane >> 4;
      float hv[4];
#pragma unroll
      for (int i = 0; i < 4; ++i) {
        float rr = sigf(aR[i]);
        float zz = sigf(aZ[i]);
        float nn = tanhf2(aNi[i] + rr*aNh[i]);
        hv[i] = (1.0f - zz)*nn + zz*hprev[i];
        hprev[i] = hv[i];
      }
      if (bb < 8 && q*4 < nrow) {
        const int j = jbase + q*4;
        const int kb = j >> 3, e = j & 7;
        s16x4 hh, ll;
#pragma unroll
        for (int i = 0; i < 4; ++i) {
          u16 h = f2bf(hv[i]);
          hh[i] = (short)h;
          ll[i] = (short)f2bf(hv[i] - bf2f(h));
        }
        u16* dst = FRu + par*PSTRIDE + hc + kb*256 + bb*8 + e;
        *(s16x4*)dst = hh;
        *(s16x4*)(dst + 128) = ll;
      }
    }
    if (s >= 5)   // coalesced out store of t = s-5 from outstage
      out[((size_t)(b0 + w)*NT + (s-5))*DD + lane] = OST[w*65 + lane];
    if (s <= 510) write_x(FRu, par, w, lane, rx*rm + rl*(1.0f - rm));
    rx = nx; rm = nm; rl = nl;
    __syncthreads();   // barrier B: h(par)/x(par) published
  }
}

__device__ __forceinline__ void wave_out(
    const float* __restrict__ OW, const float* __restrict__ OB,
    u16* FRu, float* OST,
    const float* __restrict__ X, const float* __restrict__ Mm, const float* __restrict__ Ll,
    float* __restrict__ out, int b0, int w, int lane)
{
  s16x8 Oh[4], Ol[4];
  f32x4 cO[4];
#pragma unroll
  for (int t4 = 0; t4 < 4; ++t4) {
    load_wfrag(OW, t4*16, 16, 32, 0, lane, Oh[t4], Ol[t4]);
#pragma unroll
    for (int i = 0; i < 4; ++i) cO[t4][i] = OB[t4*16 + (lane>>4)*4 + i];
  }
  const size_t gbase = ((size_t)(b0 + w))*((size_t)NT*DD) + lane;
  float rx = X[gbase], rm = Mm[gbase], rl = Ll[gbase];
  write_x(FRu, 1, w, lane, rx*rm + rl*(1.0f - rm));
  rx = X[gbase + DD]; rm = Mm[gbase + DD]; rl = Ll[gbase + DD];
  __syncthreads();

  for (int s = 0; s < NSTEP; ++s) {
    const int par = s & 1, rp = par ^ 1;
    float nx = 0.f, nm = 0.f, nl = 0.f;
    if (s <= 509) { size_t g = gbase + (size_t)(s+2)*DD; nx = X[g]; nm = Mm[g]; nl = Ll[g]; }
    if (s >= 5) {  // project h4(t = s-5)
      s16x8 bh_, bl_;
      read_b(FRu + rp*PSTRIDE + H4C, lane, bh_, bl_);
      const int bb = lane & 15, q = lane >> 4;
#pragma unroll
      for (int t4 = 0; t4 < 4; ++t4) {
        f32x4 a_ = cO[t4];
        a_ = MFMA16(Oh[t4], bh_, a_); a_ = MFMA16(Oh[t4], bl_, a_); a_ = MFMA16(Ol[t4], bh_, a_);
        if (bb < 8) {
#pragma unroll
          for (int i = 0; i < 4; ++i) OST[bb*65 + t4*16 + q*4 + i] = a_[i];
        }
      }
    }
    __syncthreads();   // barrier A
    if (s >= 5)
      out[((size_t)(b0 + w)*NT + (s-5))*DD + lane] = OST[w*65 + lane];
    if (s <= 510) write_x(FRu, par, w, lane, rx*rm + rl*(1.0f - rm));
    rx = nx; rm = nm; rl = nl;
    __syncthreads();   // barrier B
  }
}

__global__ __launch_bounds__(NTH, 1)
void gru_mfma(const float* __restrict__ X, const float* __restrict__ M, const float* __restrict__ L,
              const float* __restrict__ wih0, const float* __restrict__ whh0, const float* __restrict__ bih0, const float* __restrict__ bhh0,
              const float* __restrict__ wih1, const float* __restrict__ whh1, const float* __restrict__ bih1, const float* __restrict__ bhh1,
              const float* __restrict__ wih2, const float* __restrict__ whh2, const float* __restrict__ bih2, const float* __restrict__ bhh2,
              const float* __restrict__ wih3, const float* __restrict__ whh3, const float* __restrict__ bih3, const float* __restrict__ bhh3,
              const float* __restrict__ wih4, const float* __restrict__ whh4, const float* __restrict__ bih4, const float* __restrict__ bhh4,
              const float* __restrict__ out_w, const float* __restrict__ out_b,
              float* __restrict__ out)
{
  __shared__ __align__(16) u16 FRu[FRTOT];
  __shared__ float OST[8*65];
  const int tid = threadIdx.x;
  const int w = tid >> 6, lane = tid & 63;
  const int b0 = blockIdx.x * BB;

  for (int i = tid; i < FRTOT; i += NTH) FRu[i] = 0;
  for (int i = tid; i < 8*65; i += NTH) OST[i] = 0.f;
  __syncthreads();

  // wave roles (layer-pipelined; each wave owns matched r/z/n tiles of one j-slice)
  if (w == 0)
    wave_gru<64,32,2>(wih0,whh0,bih0,bhh0,  0, XIN0, H0C, 0, 511, FRu, OST, X,M,L, out, b0, w, lane);
  else if (w == 1)
    wave_gru<64,32,2>(wih0,whh0,bih0,bhh0, 16, XIN0, H0C, 0, 511, FRu, OST, X,M,L, out, b0, w, lane);
  else if (w == 2)
    wave_gru<32,16,1>(wih1,whh1,bih1,bhh1,  0, H0C,  H1C, 1, 512, FRu, OST, X,M,L, out, b0, w, lane);
  else if (w == 4)
    wave_gru<16, 8,1>(wih2,whh2,bih2,bhh2,  0, H1C,  H2C, 2, 513, FRu, OST, X,M,L, out, b0, w, lane);
  else if (w == 5)
    wave_gru< 8,16,1>(wih3,whh3,bih3,bhh3,  0, H2C,  H3C, 3, 514, FRu, OST, X,M,L, out, b0, w, lane);
  else if (w == 3)
    wave_gru<16,32,1>(wih4,whh4,bih4,bhh4,  0, H3C,  H4C, 4, 515, FRu, OST, X,M,L, out, b0, w, lane);
  else if (w == 6)
    wave_gru<16,32,1>(wih4,whh4,bih4,bhh4, 16, H3C,  H4C, 4, 515, FRu, OST, X,M,L, out, b0, w, lane);
  else
    wave_out(out_w, out_b, FRu, OST, X,M,L, out, b0, w, lane);
}

extern "C" void kernel_launch(void* const* d_in, const int* in_sizes, int n_in,
                              void* d_out, int out_size, void* d_ws, size_t ws_size,
                              hipStream_t stream)
{
  const float* X  = (const float*)d_in[0];
  const float* M  = (const float*)d_in[1];
  const float* L  = (const float*)d_in[2];
  const float* wp[20];
  for (int i = 0; i < 20; ++i) wp[i] = (const float*)d_in[3 + i];
  const float* ow = (const float*)d_in[23];
  const float* ob = (const float*)d_in[24];
  float* out = (float*)d_out;

  gru_mfma<<<dim3(2048 / BB), dim3(NTH), 0, stream>>>(
      X, M, L,
      wp[0], wp[1], wp[2], wp[3],
      wp[4], wp[5], wp[6], wp[7],
      wp[8], wp[9], wp[10], wp[11],
      wp[12], wp[13], wp[14], wp[15],
      wp[16], wp[17], wp[18], wp[19],
      ow, ob, out);
}

// Round 4
// 976.636 us; speedup vs baseline: 3.5538x; 1.0144x over previous
//
#include <hip/hip_runtime.h>

typedef short s16x8 __attribute__((ext_vector_type(8)));
typedef short s16x4 __attribute__((ext_vector_type(4)));
typedef float f32x4 __attribute__((ext_vector_type(4)));
typedef unsigned int u32;
typedef unsigned short u16;

#define NT 512
#define DD 64
#define BB 8
#define NTH 512

#define CHUNK 1024

// ---------- new recurrent kernel LDS (5 h-chunks per parity) ----------
#define P2STRIDE (5*CHUNK)
#define PH0 0
#define PH1 CHUNK
#define PH2 (2*CHUNK)
#define PH3 (3*CHUNK)
#define PH4 (4*CHUNK)
#define FRTOT2 (2*P2STRIDE)   // 10240 u16 = 20 KB
#define NSTEP2 518            // 512 + 6 pipeline stages (extra store stage)

// ---------- fallback (round-3) LDS ----------
#define PSTRIDE (7*CHUNK)
#define XIN0 0
#define H0C (2*CHUNK)
#define H1C (3*CHUNK)
#define H2C (4*CHUNK)
#define H3C (5*CHUNK)
#define H4C (6*CHUNK)
#define FRTOT (2*PSTRIDE)
#define NSTEP_FB 517

#define MFMA16(A,B,C) __builtin_amdgcn_mfma_f32_16x16x32_bf16(A,B,C,0,0,0)

__device__ __forceinline__ float sigf(float x){ return 1.0f/(1.0f+__expf(-x)); }
__device__ __forceinline__ float tanhf2(float x){ return 2.0f/(1.0f+__expf(-2.0f*x)) - 1.0f; }

__device__ __forceinline__ u16 f2bf(float f) {
  u32 u = __builtin_bit_cast(u32, f);
  return (u16)((u + 0x7fffu + ((u >> 16) & 1u)) >> 16);
}
__device__ __forceinline__ float bf2f(u16 h) {
  u32 u = ((u32)h) << 16;
  return __builtin_bit_cast(float, u);
}

// A-fragment: lane holds A[row0 + (lane&15)][kbase + (lane>>4)*8 + e], zero-padded.
__device__ __forceinline__ void load_wfrag(const float* __restrict__ W, int row0, int nrow, int din,
                                           int kbase, int lane, s16x8& hi, s16x8& lo)
{
  const int m = lane & 15, kb = lane >> 4;
#pragma unroll
  for (int e = 0; e < 8; ++e) {
    int k = kbase + kb*8 + e;
    float v = (m < nrow && k < din) ? W[(size_t)(row0 + m)*din + k] : 0.0f;
    u16 h = f2bf(v);
    hi[e] = (short)h;
    lo[e] = (short)f2bf(v - bf2f(h));
  }
}

// B-fragment read: lane reads B[k=(lane>>4)*8+e][col=lane&15] (hi at +0, lo at +128)
__device__ __forceinline__ void read_b(const u16* base, int lane, s16x8& hi, s16x8& lo)
{
  const int off = ((lane >> 4) << 8) + ((lane & 15) << 3);
  hi = *(const s16x8*)(base + off);
  lo = *(const s16x8*)(base + off + 128);
}

// gate combine + h write (shared by all recurrent waves)
__device__ __forceinline__ void combine_write(
    f32x4 aR, f32x4 aZ, f32x4 aNi, f32x4 aNh,
    float (&hprev)[4], u16* hdst_base, int jbase, int nrow, int lane)
{
  const int bb = lane & 15, q = lane >> 4;
  float hv[4];
#pragma unroll
  for (int i = 0; i < 4; ++i) {
    float rr = sigf(aR[i]);
    float zz = sigf(aZ[i]);
    float nn = tanhf2(aNi[i] + rr*aNh[i]);
    hv[i] = (1.0f - zz)*nn + zz*hprev[i];
    hprev[i] = hv[i];
  }
  if (bb < 8 && q*4 < nrow) {
    const int j = jbase + q*4;
    const int kb = j >> 3, e = j & 7;
    s16x4 hh, ll;
#pragma unroll
    for (int i = 0; i < 4; ++i) {
      u16 h = f2bf(hv[i]);
      hh[i] = (short)h;
      ll[i] = (short)f2bf(hv[i] - bf2f(h));
    }
    u16* dst = hdst_base + kb*256 + bb*8 + e;
    *(s16x4*)dst = hh;
    *(s16x4*)(dst + 128) = ll;
  }
}

// =====================================================================
// Phase 1: gi0[b][t][96] = Wih0 @ x_imp(b,t) + bih0   (no recurrence)
// =====================================================================
__global__ __launch_bounds__(256)
void gi0_gemm(const float* __restrict__ X, const float* __restrict__ M, const float* __restrict__ L,
              const float* __restrict__ wih0, const float* __restrict__ bih0,
              float* __restrict__ gi)
{
  __shared__ u32 xs[128*65];   // packed (hi | lo<<16) bf16 of imputed x, [t][d], pad 65
  const int tid = threadIdx.x;
  const int wv = tid >> 6, lane = tid & 63;
  const int q = lane >> 4;
  const int b = blockIdx.x >> 2;
  const int t0 = (blockIdx.x & 3) * 128;
  const size_t base = ((size_t)b*NT + t0)*DD;

  for (int i = tid; i < 128*64; i += 256) {
    const int t = i >> 6, d = i & 63;
    float x = X[base+i], m = M[base+i], l = L[base+i];
    float v = x*m + l*(1.0f - m);
    u16 h = f2bf(v);
    u16 lo2 = f2bf(v - bf2f(h));
    xs[t*65 + d] = (u32)h | ((u32)lo2 << 16);
  }

  s16x8 Ah[6][2], Al[6][2];
  f32x4 cb[6];
#pragma unroll
  for (int tile = 0; tile < 6; ++tile) {
#pragma unroll
    for (int c = 0; c < 2; ++c)
      load_wfrag(wih0, tile*16, 16, 64, c*32, lane, Ah[tile][c], Al[tile][c]);
#pragma unroll
    for (int i = 0; i < 4; ++i) cb[tile][i] = bih0[tile*16 + q*4 + i];
  }
  __syncthreads();

#pragma unroll
  for (int g2 = 0; g2 < 2; ++g2) {
    const int tloc = g2*64 + wv*16 + (lane & 15);
    s16x8 Bh[2], Bl[2];
#pragma unroll
    for (int c = 0; c < 2; ++c) {
      const u32* p = &xs[tloc*65 + c*32 + q*8];
#pragma unroll
      for (int e = 0; e < 8; ++e) {
        u32 v = p[e];
        Bh[c][e] = (short)(v & 0xffffu);
        Bl[c][e] = (short)(v >> 16);
      }
    }
    float* gp = gi + ((size_t)b*NT + t0 + tloc)*96 + q*4;
#pragma unroll
    for (int tile = 0; tile < 6; ++tile) {
      f32x4 acc = cb[tile];
#pragma unroll
      for (int c = 0; c < 2; ++c) {
        acc = MFMA16(Ah[tile][c], Bh[c], acc);
        acc = MFMA16(Ah[tile][c], Bl[c], acc);
        acc = MFMA16(Al[tile][c], Bh[c], acc);
      }
      *(f32x4*)(gp + tile*16) = acc;
    }
  }
}

// =====================================================================
// Phase 2: recurrent kernel (single barrier per step, gi0-fed layer 0)
// =====================================================================
__device__ __forceinline__ void wave_l0(
    const float* __restrict__ Whh, const float* __restrict__ bhh,
    const float* __restrict__ gi, int jbase,
    u16* FRu, float* OST, float* __restrict__ out, int b0, int w, int lane)
{
  s16x8 Ahh[3], Ahl[3];
#pragma unroll
  for (int g = 0; g < 3; ++g)
    load_wfrag(Whh, g*32 + jbase, 16, 32, 0, lane, Ahh[g], Ahl[g]);
  const int q = lane >> 4;
  f32x4 cRh, cZh, cNh;
#pragma unroll
  for (int i = 0; i < 4; ++i) {
    int j = jbase + q*4 + i;
    cRh[i] = bhh[j]; cZh[i] = bhh[32+j]; cNh[i] = bhh[64+j];
  }
  float hprev[4] = {0.f,0.f,0.f,0.f};

  const size_t grow = (size_t)(b0 + (lane & 7)) * ((size_t)NT*96);
  f32x4 gR, gZ, gN;
  {
    const float* p = gi + grow + jbase + q*4;
    gR = *(const f32x4*)(p); gZ = *(const f32x4*)(p+32); gN = *(const f32x4*)(p+64);
  }
  for (int s = 0; s < NSTEP2; ++s) {
    const int par = s & 1, rp = par ^ 1;
    f32x4 nR, nZ, nN;
    if (s < 511) {
      const float* p = gi + grow + (size_t)(s+1)*96 + jbase + q*4;
      nR = *(const f32x4*)(p); nZ = *(const f32x4*)(p+32); nN = *(const f32x4*)(p+64);
    }
    if (s <= 511) {
      f32x4 aR = gR + cRh, aZ = gZ + cZh, aNi = gN, aNh = cNh;
      s16x8 bh_, bl_;
      read_b(FRu + rp*P2STRIDE + PH0, lane, bh_, bl_);
      aR  = MFMA16(Ahh[0], bh_, aR);  aR  = MFMA16(Ahh[0], bl_, aR);  aR  = MFMA16(Ahl[0], bh_, aR);
      aZ  = MFMA16(Ahh[1], bh_, aZ);  aZ  = MFMA16(Ahh[1], bl_, aZ);  aZ  = MFMA16(Ahl[1], bh_, aZ);
      aNh = MFMA16(Ahh[2], bh_, aNh); aNh = MFMA16(Ahh[2], bl_, aNh); aNh = MFMA16(Ahl[2], bh_, aNh);
      combine_write(aR, aZ, aNi, aNh, hprev, FRu + par*P2STRIDE + PH0, jbase, 16, lane);
    }
    if (s >= 6)
      out[((size_t)(b0 + w)*NT + (s-6))*DD + lane] = OST[rp*520 + w*65 + lane];
    gR = nR; gZ = nZ; gN = nN;
    __syncthreads();
  }
}

template<int DIN, int DH>
__device__ __forceinline__ void wave_mid(
    const float* __restrict__ Wih, const float* __restrict__ Whh,
    const float* __restrict__ bih, const float* __restrict__ bhh,
    int jbase, int xc, int hc, int s0, int s1,
    u16* FRu, float* OST, float* __restrict__ out, int b0, int w, int lane)
{
  const int nrow = (DH - jbase) < 16 ? (DH - jbase) : 16;
  s16x8 Axh[3], Axl[3], Ahh[3], Ahl[3];
#pragma unroll
  for (int g = 0; g < 3; ++g) {
    load_wfrag(Wih, g*DH + jbase, nrow, DIN, 0, lane, Axh[g], Axl[g]);
    load_wfrag(Whh, g*DH + jbase, nrow, DH, 0, lane, Ahh[g], Ahl[g]);
  }
  const int q = lane >> 4;
  f32x4 cR, cZ, cNi, cNh;
#pragma unroll
  for (int i = 0; i < 4; ++i) {
    int lr = q*4 + i;
    int j = jbase + lr;
    bool jr = lr < nrow;
    cR[i]  = jr ? bih[j] + bhh[j] : 0.f;
    cZ[i]  = jr ? bih[DH+j] + bhh[DH+j] : 0.f;
    cNi[i] = jr ? bih[2*DH+j] : 0.f;
    cNh[i] = jr ? bhh[2*DH+j] : 0.f;
  }
  float hprev[4] = {0.f,0.f,0.f,0.f};

  for (int s = 0; s < NSTEP2; ++s) {
    const int par = s & 1, rp = par ^ 1;
    if (s >= s0 && s <= s1) {
      f32x4 aR = cR, aZ = cZ, aNi = cNi, aNh = cNh;
      s16x8 bh_, bl_;
      read_b(FRu + rp*P2STRIDE + xc, lane, bh_, bl_);
      aR  = MFMA16(Axh[0], bh_, aR);  aR  = MFMA16(Axh[0], bl_, aR);  aR  = MFMA16(Axl[0], bh_, aR);
      aZ  = MFMA16(Axh[1], bh_, aZ);  aZ  = MFMA16(Axh[1], bl_, aZ);  aZ  = MFMA16(Axl[1], bh_, aZ);
      aNi = MFMA16(Axh[2], bh_, aNi); aNi = MFMA16(Axh[2], bl_, aNi); aNi = MFMA16(Axl[2], bh_, aNi);
      read_b(FRu + rp*P2STRIDE + hc, lane, bh_, bl_);
      aR  = MFMA16(Ahh[0], bh_, aR);  aR  = MFMA16(Ahh[0], bl_, aR);  aR  = MFMA16(Ahl[0], bh_, aR);
      aZ  = MFMA16(Ahh[1], bh_, aZ);  aZ  = MFMA16(Ahh[1], bl_, aZ);  aZ  = MFMA16(Ahl[1], bh_, aZ);
      aNh = MFMA16(Ahh[2], bh_, aNh); aNh = MFMA16(Ahh[2], bl_, aNh); aNh = MFMA16(Ahl[2], bh_, aNh);
      combine_write(aR, aZ, aNi, aNh, hprev, FRu + par*P2STRIDE + hc, jbase, nrow, lane);
    }
    if (s >= 6)
      out[((size_t)(b0 + w)*NT + (s-6))*DD + lane] = OST[rp*520 + w*65 + lane];
    __syncthreads();
  }
}

__device__ __forceinline__ void wave_out2(
    const float* __restrict__ OW, const float* __restrict__ OBb,
    u16* FRu, float* OST, float* __restrict__ out, int b0, int w, int lane)
{
  s16x8 Oh[4], Ol[4];
  f32x4 cO[4];
  const int q = lane >> 4;
#pragma unroll
  for (int t4 = 0; t4 < 4; ++t4) {
    load_wfrag(OW, t4*16, 16, 32, 0, lane, Oh[t4], Ol[t4]);
#pragma unroll
    for (int i = 0; i < 4; ++i) cO[t4][i] = OBb[t4*16 + q*4 + i];
  }
  for (int s = 0; s < NSTEP2; ++s) {
    const int par = s & 1, rp = par ^ 1;
    if (s >= 5 && s <= 516) {
      s16x8 bh_, bl_;
      read_b(FRu + rp*P2STRIDE + PH4, lane, bh_, bl_);
      const int bb = lane & 15;
#pragma unroll
      for (int t4 = 0; t4 < 4; ++t4) {
        f32x4 a_ = cO[t4];
        a_ = MFMA16(Oh[t4], bh_, a_); a_ = MFMA16(Oh[t4], bl_, a_); a_ = MFMA16(Ol[t4], bh_, a_);
        if (bb < 8) {
#pragma unroll
          for (int i = 0; i < 4; ++i) OST[par*520 + bb*65 + t4*16 + q*4 + i] = a_[i];
        }
      }
    }
    if (s >= 6)
      out[((size_t)(b0 + w)*NT + (s-6))*DD + lane] = OST[rp*520 + w*65 + lane];
    __syncthreads();
  }
}

__global__ __launch_bounds__(NTH, 1)
void gru_rec(const float* __restrict__ gi,
             const float* __restrict__ whh0, const float* __restrict__ bhh0,
             const float* __restrict__ wih1, const float* __restrict__ whh1, const float* __restrict__ bih1, const float* __restrict__ bhh1,
             const float* __restrict__ wih2, const float* __restrict__ whh2, const float* __restrict__ bih2, const float* __restrict__ bhh2,
             const float* __restrict__ wih3, const float* __restrict__ whh3, const float* __restrict__ bih3, const float* __restrict__ bhh3,
             const float* __restrict__ wih4, const float* __restrict__ whh4, const float* __restrict__ bih4, const float* __restrict__ bhh4,
             const float* __restrict__ out_w, const float* __restrict__ out_b,
             float* __restrict__ out)
{
  __shared__ __align__(16) u16 FRu[FRTOT2];
  __shared__ float OST[2*520];
  const int tid = threadIdx.x;
  const int w = tid >> 6, lane = tid & 63;
  const int b0 = blockIdx.x * BB;

  for (int i = tid; i < FRTOT2; i += NTH) FRu[i] = 0;
  for (int i = tid; i < 2*520; i += NTH) OST[i] = 0.f;
  __syncthreads();

  if (w == 0)
    wave_l0(whh0, bhh0, gi,  0, FRu, OST, out, b0, w, lane);
  else if (w == 1)
    wave_l0(whh0, bhh0, gi, 16, FRu, OST, out, b0, w, lane);
  else if (w == 2)
    wave_mid<32,16>(wih1,whh1,bih1,bhh1,  0, PH0, PH1, 1, 512, FRu, OST, out, b0, w, lane);
  else if (w == 4)
    wave_mid<16, 8>(wih2,whh2,bih2,bhh2,  0, PH1, PH2, 2, 513, FRu, OST, out, b0, w, lane);
  else if (w == 5)
    wave_mid< 8,16>(wih3,whh3,bih3,bhh3,  0, PH2, PH3, 3, 514, FRu, OST, out, b0, w, lane);
  else if (w == 3)
    wave_mid<16,32>(wih4,whh4,bih4,bhh4,  0, PH3, PH4, 4, 515, FRu, OST, out, b0, w, lane);
  else if (w == 6)
    wave_mid<16,32>(wih4,whh4,bih4,bhh4, 16, PH3, PH4, 4, 515, FRu, OST, out, b0, w, lane);
  else
    wave_out2(out_w, out_b, FRu, OST, out, b0, w, lane);
}

// =====================================================================
// Fallback: round-3 kernel (used only if ws_size is too small for gi0)
// =====================================================================
__device__ __forceinline__ void write_x(u16* FRu, int par, int w, int lane, float v)
{
  const int d = lane;
  const int chunk = d >> 5, kb = (d >> 3) & 3, e = d & 7;
  u16 h = f2bf(v);
  u16 l2 = f2bf(v - bf2f(h));
  u16* p = FRu + par*PSTRIDE + XIN0 + chunk*CHUNK + kb*256 + w*8 + e;
  p[0] = h; p[128] = l2;
}

template<int DIN, int DH, int NXC>
__device__ __forceinline__ void wave_gru_fb(
    const float* __restrict__ Wih, const float* __restrict__ Whh,
    const float* __restrict__ bih, const float* __restrict__ bhh,
    int jbase, int xc, int hc, int s0, int s1,
    u16* FRu, float* OST,
    const float* __restrict__ X, const float* __restrict__ Mm, const float* __restrict__ Ll,
    float* __restrict__ out, int b0, int w, int lane)
{
  const int nrow = (DH - jbase) < 16 ? (DH - jbase) : 16;
  s16x8 Axh[3][NXC], Axl[3][NXC], Ahh[3], Ahl[3];
#pragma unroll
  for (int g = 0; g < 3; ++g) {
#pragma unroll
    for (int c = 0; c < NXC; ++c)
      load_wfrag(Wih, g*DH + jbase, nrow, DIN, c*32, lane, Axh[g][c], Axl[g][c]);
    load_wfrag(Whh, g*DH + jbase, nrow, DH, 0, lane, Ahh[g], Ahl[g]);
  }
  f32x4 cR, cZ, cNi, cNh;
  {
    const int q = lane >> 4;
#pragma unroll
    for (int i = 0; i < 4; ++i) {
      int lr = q*4 + i;
      int j = jbase + lr;
      bool jr = lr < nrow;
      cR[i]  = jr ? bih[j] + bhh[j] : 0.f;
      cZ[i]  = jr ? bih[DH+j] + bhh[DH+j] : 0.f;
      cNi[i] = jr ? bih[2*DH+j] : 0.f;
      cNh[i] = jr ? bhh[2*DH+j] : 0.f;
    }
  }
  float hprev[4] = {0.f, 0.f, 0.f, 0.f};

  const size_t gbase = ((size_t)(b0 + w))*((size_t)NT*DD) + lane;
  float rx = X[gbase], rm = Mm[gbase], rl = Ll[gbase];
  write_x(FRu, 1, w, lane, rx*rm + rl*(1.0f - rm));
  rx = X[gbase + DD]; rm = Mm[gbase + DD]; rl = Ll[gbase + DD];
  __syncthreads();

  for (int s = 0; s < NSTEP_FB; ++s) {
    const int par = s & 1, rp = par ^ 1;
    float nx = 0.f, nm = 0.f, nl = 0.f;
    if (s <= 509) {
      size_t g = gbase + (size_t)(s+2)*DD;
      nx = X[g]; nm = Mm[g]; nl = Ll[g];
    }
    f32x4 aR = cR, aZ = cZ, aNi = cNi, aNh = cNh;
    const bool run = (s >= s0) && (s <= s1);
    if (run) {
      const u16* RB = FRu + rp*PSTRIDE;
      s16x8 bh_, bl_;
#pragma unroll
      for (int c = 0; c < NXC; ++c) {
        read_b(RB + xc + c*CHUNK, lane, bh_, bl_);
        aR  = MFMA16(Axh[0][c], bh_, aR);  aR  = MFMA16(Axh[0][c], bl_, aR);  aR  = MFMA16(Axl[0][c], bh_, aR);
        aZ  = MFMA16(Axh[1][c], bh_, aZ);  aZ  = MFMA16(Axh[1][c], bl_, aZ);  aZ  = MFMA16(Axl[1][c], bh_, aZ);
        aNi = MFMA16(Axh[2][c], bh_, aNi); aNi = MFMA16(Axh[2][c], bl_, aNi); aNi = MFMA16(Axl[2][c], bh_, aNi);
      }
      read_b(RB + hc, lane, bh_, bl_);
      aR  = MFMA16(Ahh[0], bh_, aR);  aR  = MFMA16(Ahh[0], bl_, aR);  aR  = MFMA16(Ahl[0], bh_, aR);
      aZ  = MFMA16(Ahh[1], bh_, aZ);  aZ  = MFMA16(Ahh[1], bl_, aZ);  aZ  = MFMA16(Ahl[1], bh_, aZ);
      aNh = MFMA16(Ahh[2], bh_, aNh); aNh = MFMA16(Ahh[2], bl_, aNh); aNh = MFMA16(Ahl[2], bh_, aNh);
    }
    __syncthreads();

    if (run)
      combine_write(aR, aZ, aNi, aNh, hprev, FRu + par*PSTRIDE + hc, jbase, nrow, lane);
    if (s >= 5)
      out[((size_t)(b0 + w)*NT + (s-5))*DD + lane] = OST[w*65 + lane];
    if (s <= 510) write_x(FRu, par, w, lane, rx*rm + rl*(1.0f - rm));
    rx = nx; rm = nm; rl = nl;
    __syncthreads();
  }
}

__device__ __forceinline__ void wave_out_fb(
    const float* __restrict__ OW, const float* __restrict__ OBb,
    u16* FRu, float* OST,
    const float* __restrict__ X, const float* __restrict__ Mm, const float* __restrict__ Ll,
    float* __restrict__ out, int b0, int w, int lane)
{
  s16x8 Oh[4], Ol[4];
  f32x4 cO[4];
#pragma unroll
  for (int t4 = 0; t4 < 4; ++t4) {
    load_wfrag(OW, t4*16, 16, 32, 0, lane, Oh[t4], Ol[t4]);
#pragma unroll
    for (int i = 0; i < 4; ++i) cO[t4][i] = OBb[t4*16 + (lane>>4)*4 + i];
  }
  const size_t gbase = ((size_t)(b0 + w))*((size_t)NT*DD) + lane;
  float rx = X[gbase], rm = Mm[gbase], rl = Ll[gbase];
  write_x(FRu, 1, w, lane, rx*rm + rl*(1.0f - rm));
  rx = X[gbase + DD]; rm = Mm[gbase + DD]; rl = Ll[gbase + DD];
  __syncthreads();

  for (int s = 0; s < NSTEP_FB; ++s) {
    const int par = s & 1, rp = par ^ 1;
    float nx = 0.f, nm = 0.f, nl = 0.f;
    if (s <= 509) { size_t g = gbase + (size_t)(s+2)*DD; nx = X[g]; nm = Mm[g]; nl = Ll[g]; }
    if (s >= 5) {
      s16x8 bh_, bl_;
      read_b(FRu + rp*PSTRIDE + H4C, lane, bh_, bl_);
      const int bb = lane & 15, q = lane >> 4;
#pragma unroll
      for (int t4 = 0; t4 < 4; ++t4) {
        f32x4 a_ = cO[t4];
        a_ = MFMA16(Oh[t4], bh_, a_); a_ = MFMA16(Oh[t4], bl_, a_); a_ = MFMA16(Ol[t4], bh_, a_);
        if (bb < 8) {
#pragma unroll
          for (int i = 0; i < 4; ++i) OST[bb*65 + t4*16 + q*4 + i] = a_[i];
        }
      }
    }
    __syncthreads();
    if (s >= 5)
      out[((size_t)(b0 + w)*NT + (s-5))*DD + lane] = OST[w*65 + lane];
    if (s <= 510) write_x(FRu, par, w, lane, rx*rm + rl*(1.0f - rm));
    rx = nx; rm = nm; rl = nl;
    __syncthreads();
  }
}

__global__ __launch_bounds__(NTH, 1)
void gru_mfma(const float* __restrict__ X, const float* __restrict__ M, const float* __restrict__ L,
              const float* __restrict__ wih0, const float* __restrict__ whh0, const float* __restrict__ bih0, const float* __restrict__ bhh0,
              const float* __restrict__ wih1, const float* __restrict__ whh1, const float* __restrict__ bih1, const float* __restrict__ bhh1,
              const float* __restrict__ wih2, const float* __restrict__ whh2, const float* __restrict__ bih2, const float* __restrict__ bhh2,
              const float* __restrict__ wih3, const float* __restrict__ whh3, const float* __restrict__ bih3, const float* __restrict__ bhh3,
              const float* __restrict__ wih4, const float* __restrict__ whh4, const float* __restrict__ bih4, const float* __restrict__ bhh4,
              const float* __restrict__ out_w, const float* __restrict__ out_b,
              float* __restrict__ out)
{
  __shared__ __align__(16) u16 FRu[FRTOT];
  __shared__ float OST[8*65];
  const int tid = threadIdx.x;
  const int w = tid >> 6, lane = tid & 63;
  const int b0 = blockIdx.x * BB;

  for (int i = tid; i < FRTOT; i += NTH) FRu[i] = 0;
  for (int i = tid; i < 8*65; i += NTH) OST[i] = 0.f;
  __syncthreads();

  if (w == 0)
    wave_gru_fb<64,32,2>(wih0,whh0,bih0,bhh0,  0, XIN0, H0C, 0, 511, FRu, OST, X,M,L, out, b0, w, lane);
  else if (w == 1)
    wave_gru_fb<64,32,2>(wih0,whh0,bih0,bhh0, 16, XIN0, H0C, 0, 511, FRu, OST, X,M,L, out, b0, w, lane);
  else if (w == 2)
    wave_gru_fb<32,16,1>(wih1,whh1,bih1,bhh1,  0, H0C,  H1C, 1, 512, FRu, OST, X,M,L, out, b0, w, lane);
  else if (w == 4)
    wave_gru_fb<16, 8,1>(wih2,whh2,bih2,bhh2,  0, H1C,  H2C, 2, 513, FRu, OST, X,M,L, out, b0, w, lane);
  else if (w == 5)
    wave_gru_fb< 8,16,1>(wih3,whh3,bih3,bhh3,  0, H2C,  H3C, 3, 514, FRu, OST, X,M,L, out, b0, w, lane);
  else if (w == 3)
    wave_gru_fb<16,32,1>(wih4,whh4,bih4,bhh4,  0, H3C,  H4C, 4, 515, FRu, OST, X,M,L, out, b0, w, lane);
  else if (w == 6)
    wave_gru_fb<16,32,1>(wih4,whh4,bih4,bhh4, 16, H3C,  H4C, 4, 515, FRu, OST, X,M,L, out, b0, w, lane);
  else
    wave_out_fb(out_w, out_b, FRu, OST, X,M,L, out, b0, w, lane);
}

extern "C" void kernel_launch(void* const* d_in, const int* in_sizes, int n_in,
                              void* d_out, int out_size, void* d_ws, size_t ws_size,
                              hipStream_t stream)
{
  const float* X  = (const float*)d_in[0];
  const float* M  = (const float*)d_in[1];
  const float* L  = (const float*)d_in[2];
  const float* wp[20];
  for (int i = 0; i < 20; ++i) wp[i] = (const float*)d_in[3 + i];
  const float* ow = (const float*)d_in[23];
  const float* ob = (const float*)d_in[24];
  float* out = (float*)d_out;

  const size_t gi_bytes = (size_t)2048 * NT * 96 * sizeof(float);  // 402,653,184
  if (ws_size >= gi_bytes) {
    float* gi = (float*)d_ws;
    gi0_gemm<<<dim3(2048*4), dim3(256), 0, stream>>>(X, M, L, wp[0], wp[2], gi);
    gru_rec<<<dim3(2048 / BB), dim3(NTH), 0, stream>>>(
        gi, wp[1], wp[3],
        wp[4], wp[5], wp[6], wp[7],
        wp[8], wp[9], wp[10], wp[11],
        wp[12], wp[13], wp[14], wp[15],
        wp[16], wp[17], wp[18], wp[19],
        ow, ob, out);
  } else {
    gru_mfma<<<dim3(2048 / BB), dim3(NTH), 0, stream>>>(
        X, M, L,
        wp[0], wp[1], wp[2], wp[3],
        wp[4], wp[5], wp[6], wp[7],
        wp[8], wp[9], wp[10], wp[11],
        wp[12], wp[13], wp[14], wp[15],
        wp[16], wp[17], wp[18], wp[19],
        ow, ob, out);
  }
}

// Round 5
// 840.145 us; speedup vs baseline: 4.1312x; 1.1625x over previous
//
#include <hip/hip_runtime.h>

typedef short s16x8 __attribute__((ext_vector_type(8)));
typedef short s16x4 __attribute__((ext_vector_type(4)));
typedef float f32x4 __attribute__((ext_vector_type(4)));
typedef unsigned int u32;
typedef unsigned short u16;

#define NT 512
#define DD 64
#define BB 8
#define NTH 512

#define CHUNK 1024

// ---------- recurrent kernel LDS (5 h-chunks per parity) ----------
#define P2STRIDE (5*CHUNK)
#define PH0 0
#define PH1 CHUNK
#define PH2 (2*CHUNK)
#define PH3 (3*CHUNK)
#define PH4 (4*CHUNK)
#define FRTOT2 (2*P2STRIDE)   // 10240 u16 = 20 KB
#define NSTEP2 517            // 512 + 5 pipeline stages

// ---------- fallback (round-3) LDS ----------
#define PSTRIDE (7*CHUNK)
#define XIN0 0
#define H0C (2*CHUNK)
#define H1C (3*CHUNK)
#define H2C (4*CHUNK)
#define H3C (5*CHUNK)
#define H4C (6*CHUNK)
#define FRTOT (2*PSTRIDE)
#define NSTEP_FB 517

#define MFMA16(A,B,C) __builtin_amdgcn_mfma_f32_16x16x32_bf16(A,B,C,0,0,0)

__device__ __forceinline__ float sigf(float x){ return 1.0f/(1.0f+__expf(-x)); }
__device__ __forceinline__ float tanhf2(float x){ return 2.0f/(1.0f+__expf(-2.0f*x)) - 1.0f; }

__device__ __forceinline__ u16 f2bf(float f) {
  u32 u = __builtin_bit_cast(u32, f);
  return (u16)((u + 0x7fffu + ((u >> 16) & 1u)) >> 16);
}
__device__ __forceinline__ float bf2f(u16 h) {
  u32 u = ((u32)h) << 16;
  return __builtin_bit_cast(float, u);
}

// barrier WITHOUT the vmcnt(0) drain: LDS visibility only (global ops drain at use)
__device__ __forceinline__ void soft_barrier() {
  asm volatile("s_waitcnt lgkmcnt(0)" ::: "memory");
  __builtin_amdgcn_s_barrier();
  asm volatile("" ::: "memory");
}

__device__ __forceinline__ u32 cvtpk_bf16(float a, float b) {
  u32 r;
  asm("v_cvt_pk_bf16_f32 %0, %1, %2" : "=v"(r) : "v"(a), "v"(b));
  return r;
}

// A-fragment: lane holds A[row0 + (lane&15)][kbase + (lane>>4)*8 + e], zero-padded.
__device__ __forceinline__ void load_wfrag(const float* __restrict__ W, int row0, int nrow, int din,
                                           int kbase, int lane, s16x8& hi, s16x8& lo)
{
  const int m = lane & 15, kb = lane >> 4;
#pragma unroll
  for (int e = 0; e < 8; ++e) {
    int k = kbase + kb*8 + e;
    float v = (m < nrow && k < din) ? W[(size_t)(row0 + m)*din + k] : 0.0f;
    u16 h = f2bf(v);
    hi[e] = (short)h;
    lo[e] = (short)f2bf(v - bf2f(h));
  }
}

// B-fragment read: lane reads B[k=(lane>>4)*8+e][col=lane&15] (hi at +0, lo at +128)
__device__ __forceinline__ void read_b(const u16* base, int lane, s16x8& hi, s16x8& lo)
{
  const int off = ((lane >> 4) << 8) + ((lane & 15) << 3);
  hi = *(const s16x8*)(base + off);
  lo = *(const s16x8*)(base + off + 128);
}

// gate combine + h write (cvt_pk packing)
__device__ __forceinline__ void combine_write2(
    f32x4 aR, f32x4 aZ, f32x4 aNi, f32x4 aNh,
    float (&hprev)[4], u16* hdst_base, int jbase, int nrow, int lane)
{
  const int bb = lane & 15, q = lane >> 4;
  float hv[4];
#pragma unroll
  for (int i = 0; i < 4; ++i) {
    float rr = sigf(aR[i]);
    float zz = sigf(aZ[i]);
    float nn = tanhf2(aNi[i] + rr*aNh[i]);
    hv[i] = (1.0f - zz)*nn + zz*hprev[i];
    hprev[i] = hv[i];
  }
  if (bb < 8 && q*4 < nrow) {
    const int j = jbase + q*4;
    u16* dst = hdst_base + ((j >> 3) << 8) + bb*8 + (j & 7);
    u32 p01 = cvtpk_bf16(hv[0], hv[1]);
    u32 p23 = cvtpk_bf16(hv[2], hv[3]);
    float h0 = __builtin_bit_cast(float, p01 << 16);
    float h1 = __builtin_bit_cast(float, p01 & 0xffff0000u);
    float h2 = __builtin_bit_cast(float, p23 << 16);
    float h3 = __builtin_bit_cast(float, p23 & 0xffff0000u);
    u32 q01 = cvtpk_bf16(hv[0]-h0, hv[1]-h1);
    u32 q23 = cvtpk_bf16(hv[2]-h2, hv[3]-h3);
    uint2 hp_; hp_.x = p01; hp_.y = p23;
    uint2 lp_; lp_.x = q01; lp_.y = q23;
    *(uint2*)dst = hp_;
    *(uint2*)(dst + 128) = lp_;
  }
}

// legacy combine (fallback kernel)
__device__ __forceinline__ void combine_write(
    f32x4 aR, f32x4 aZ, f32x4 aNi, f32x4 aNh,
    float (&hprev)[4], u16* hdst_base, int jbase, int nrow, int lane)
{
  const int bb = lane & 15, q = lane >> 4;
  float hv[4];
#pragma unroll
  for (int i = 0; i < 4; ++i) {
    float rr = sigf(aR[i]);
    float zz = sigf(aZ[i]);
    float nn = tanhf2(aNi[i] + rr*aNh[i]);
    hv[i] = (1.0f - zz)*nn + zz*hprev[i];
    hprev[i] = hv[i];
  }
  if (bb < 8 && q*4 < nrow) {
    const int j = jbase + q*4;
    const int kb = j >> 3, e = j & 7;
    s16x4 hh, ll;
#pragma unroll
    for (int i = 0; i < 4; ++i) {
      u16 h = f2bf(hv[i]);
      hh[i] = (short)h;
      ll[i] = (short)f2bf(hv[i] - bf2f(h));
    }
    u16* dst = hdst_base + kb*256 + bb*8 + e;
    *(s16x4*)dst = hh;
    *(s16x4*)(dst + 128) = ll;
  }
}

// =====================================================================
// Phase 1: gi0[b][t][96] = Wih0 @ x_imp(b,t) + bih0 (+bhh0 for r,z rows)
// =====================================================================
__global__ __launch_bounds__(256)
void gi0_gemm(const float* __restrict__ X, const float* __restrict__ M, const float* __restrict__ L,
              const float* __restrict__ wih0, const float* __restrict__ bih0,
              const float* __restrict__ bhh0,
              float* __restrict__ gi)
{
  __shared__ u32 xs[128*65];   // packed (hi | lo<<16) bf16 of imputed x, [t][d], pad 65
  const int tid = threadIdx.x;
  const int wv = tid >> 6, lane = tid & 63;
  const int q = lane >> 4;
  const int b = blockIdx.x >> 2;
  const int t0 = (blockIdx.x & 3) * 128;
  const size_t base = ((size_t)b*NT + t0)*DD;

  for (int i = tid; i < 128*64; i += 256) {
    float x = X[base+i], m = M[base+i], l = L[base+i];
    float v = x*m + l*(1.0f - m);
    u16 h = f2bf(v);
    u16 lo2 = f2bf(v - bf2f(h));
    const int t = i >> 6, d = i & 63;
    xs[t*65 + d] = (u32)h | ((u32)lo2 << 16);
  }

  s16x8 Ah[6][2], Al[6][2];
  f32x4 cb[6];
#pragma unroll
  for (int tile = 0; tile < 6; ++tile) {
#pragma unroll
    for (int c = 0; c < 2; ++c)
      load_wfrag(wih0, tile*16, 16, 64, c*32, lane, Ah[tile][c], Al[tile][c]);
#pragma unroll
    for (int i = 0; i < 4; ++i) {
      int row = tile*16 + q*4 + i;
      float bv = bih0[row];
      if (tile < 4) bv += bhh0[row];   // fold bhh r,z parts (rows 0..63)
      cb[tile][i] = bv;
    }
  }
  __syncthreads();

#pragma unroll
  for (int g2 = 0; g2 < 2; ++g2) {
    const int tloc = g2*64 + wv*16 + (lane & 15);
    s16x8 Bh[2], Bl[2];
#pragma unroll
    for (int c = 0; c < 2; ++c) {
      const u32* p = &xs[tloc*65 + c*32 + q*8];
#pragma unroll
      for (int e = 0; e < 8; ++e) {
        u32 v = p[e];
        Bh[c][e] = (short)(v & 0xffffu);
        Bl[c][e] = (short)(v >> 16);
      }
    }
    float* gp = gi + ((size_t)b*NT + t0 + tloc)*96 + q*4;
#pragma unroll
    for (int tile = 0; tile < 6; ++tile) {
      f32x4 acc = cb[tile];
#pragma unroll
      for (int c = 0; c < 2; ++c) {
        acc = MFMA16(Ah[tile][c], Bh[c], acc);
        acc = MFMA16(Ah[tile][c], Bl[c], acc);
        acc = MFMA16(Al[tile][c], Bh[c], acc);
      }
      *(f32x4*)(gp + tile*16) = acc;
    }
  }
}

// =====================================================================
// Phase 2: recurrent kernel (soft barriers, direct out stores)
// =====================================================================
__device__ __forceinline__ void wave_l0(
    const float* __restrict__ Whh, const float* __restrict__ bhh,
    const float* __restrict__ gi, int jbase,
    u16* FRu, int b0, int lane)
{
  s16x8 Ahh[3], Ahl[3];
#pragma unroll
  for (int g = 0; g < 3; ++g)
    load_wfrag(Whh, g*32 + jbase, 16, 32, 0, lane, Ahh[g], Ahl[g]);
  const int q = lane >> 4;
  f32x4 cNh;
#pragma unroll
  for (int i = 0; i < 4; ++i) cNh[i] = bhh[64 + jbase + q*4 + i];
  float hprev[4] = {0.f,0.f,0.f,0.f};

  const float* gp = gi + (size_t)(b0 + (lane & 7)) * ((size_t)NT*96) + jbase + q*4;
  f32x4 gR0, gZ0, gN0, gR1, gZ1, gN1;
  gR0 = *(const f32x4*)(gp); gZ0 = *(const f32x4*)(gp+32); gN0 = *(const f32x4*)(gp+64); gp += 96;
  gR1 = *(const f32x4*)(gp); gZ1 = *(const f32x4*)(gp+32); gN1 = *(const f32x4*)(gp+64); gp += 96;

  for (int s = 0; s < NSTEP2; ++s) {
    const int par = s & 1, rp = par ^ 1;
    f32x4 gR2 = {}, gZ2 = {}, gN2 = {};
    if (s + 2 < NT) {
      gR2 = *(const f32x4*)(gp); gZ2 = *(const f32x4*)(gp+32); gN2 = *(const f32x4*)(gp+64); gp += 96;
    }
    if (s < NT) {
      f32x4 aR = gR0, aZ = gZ0, aNi = gN0, aNh = cNh;   // biases pre-folded in gi
      s16x8 bh_, bl_;
      read_b(FRu + rp*P2STRIDE + PH0, lane, bh_, bl_);
      aR  = MFMA16(Ahh[0], bh_, aR);  aR  = MFMA16(Ahh[0], bl_, aR);  aR  = MFMA16(Ahl[0], bh_, aR);
      aZ  = MFMA16(Ahh[1], bh_, aZ);  aZ  = MFMA16(Ahh[1], bl_, aZ);  aZ  = MFMA16(Ahl[1], bh_, aZ);
      aNh = MFMA16(Ahh[2], bh_, aNh); aNh = MFMA16(Ahh[2], bl_, aNh); aNh = MFMA16(Ahl[2], bh_, aNh);
      combine_write2(aR, aZ, aNi, aNh, hprev, FRu + par*P2STRIDE + PH0, jbase, 16, lane);
    }
    gR0 = gR1; gZ0 = gZ1; gN0 = gN1;
    gR1 = gR2; gZ1 = gZ2; gN1 = gN2;
    soft_barrier();
  }
}

template<int DIN, int DH>
__device__ __forceinline__ void wave_mid(
    const float* __restrict__ Wih, const float* __restrict__ Whh,
    const float* __restrict__ bih, const float* __restrict__ bhh,
    int jbase, int xc, int hc, int s0, int s1,
    u16* FRu, int b0, int lane)
{
  const int nrow = (DH - jbase) < 16 ? (DH - jbase) : 16;
  s16x8 Axh[3], Axl[3], Ahh[3], Ahl[3];
#pragma unroll
  for (int g = 0; g < 3; ++g) {
    load_wfrag(Wih, g*DH + jbase, nrow, DIN, 0, lane, Axh[g], Axl[g]);
    load_wfrag(Whh, g*DH + jbase, nrow, DH, 0, lane, Ahh[g], Ahl[g]);
  }
  const int q = lane >> 4;
  f32x4 cR, cZ, cNi, cNh;
#pragma unroll
  for (int i = 0; i < 4; ++i) {
    int lr = q*4 + i;
    int j = jbase + lr;
    bool jr = lr < nrow;
    cR[i]  = jr ? bih[j] + bhh[j] : 0.f;
    cZ[i]  = jr ? bih[DH+j] + bhh[DH+j] : 0.f;
    cNi[i] = jr ? bih[2*DH+j] : 0.f;
    cNh[i] = jr ? bhh[2*DH+j] : 0.f;
  }
  float hprev[4] = {0.f,0.f,0.f,0.f};

  for (int s = 0; s < NSTEP2; ++s) {
    const int par = s & 1, rp = par ^ 1;
    if (s >= s0 && s <= s1) {
      f32x4 aR = cR, aZ = cZ, aNi = cNi, aNh = cNh;
      s16x8 bh_, bl_;
      read_b(FRu + rp*P2STRIDE + xc, lane, bh_, bl_);
      aR  = MFMA16(Axh[0], bh_, aR);  aR  = MFMA16(Axh[0], bl_, aR);  aR  = MFMA16(Axl[0], bh_, aR);
      aZ  = MFMA16(Axh[1], bh_, aZ);  aZ  = MFMA16(Axh[1], bl_, aZ);  aZ  = MFMA16(Axl[1], bh_, aZ);
      aNi = MFMA16(Axh[2], bh_, aNi); aNi = MFMA16(Axh[2], bl_, aNi); aNi = MFMA16(Axl[2], bh_, aNi);
      read_b(FRu + rp*P2STRIDE + hc, lane, bh_, bl_);
      aR  = MFMA16(Ahh[0], bh_, aR);  aR  = MFMA16(Ahh[0], bl_, aR);  aR  = MFMA16(Ahl[0], bh_, aR);
      aZ  = MFMA16(Ahh[1], bh_, aZ);  aZ  = MFMA16(Ahh[1], bl_, aZ);  aZ  = MFMA16(Ahl[1], bh_, aZ);
      aNh = MFMA16(Ahh[2], bh_, aNh); aNh = MFMA16(Ahh[2], bl_, aNh); aNh = MFMA16(Ahl[2], bh_, aNh);
      combine_write2(aR, aZ, aNi, aNh, hprev, FRu + par*P2STRIDE + hc, jbase, nrow, lane);
    }
    soft_barrier();
  }
}

__device__ __forceinline__ void wave_out2(
    const float* __restrict__ OW, const float* __restrict__ OBb,
    u16* FRu, float* __restrict__ out, int b0, int lane)
{
  s16x8 Oh[4], Ol[4];
  f32x4 cO[4];
  const int q = lane >> 4, bb = lane & 15;
#pragma unroll
  for (int t4 = 0; t4 < 4; ++t4) {
    load_wfrag(OW, t4*16, 16, 32, 0, lane, Oh[t4], Ol[t4]);
#pragma unroll
    for (int i = 0; i < 4; ++i) cO[t4][i] = OBb[t4*16 + q*4 + i];
  }
  float* op = out + ((size_t)(b0 + (bb & 7))*NT)*DD + q*4;   // t=0 base for this lane

  for (int s = 0; s < NSTEP2; ++s) {
    const int rp = (s & 1) ^ 1;
    if (s >= 5) {
      s16x8 bh_, bl_;
      read_b(FRu + rp*P2STRIDE + PH4, lane, bh_, bl_);
#pragma unroll
      for (int t4 = 0; t4 < 4; ++t4) {
        f32x4 a_ = cO[t4];
        a_ = MFMA16(Oh[t4], bh_, a_); a_ = MFMA16(Oh[t4], bl_, a_); a_ = MFMA16(Ol[t4], bh_, a_);
        if (bb < 8) *(f32x4*)(op + t4*16) = a_;   // direct C-frag store (64B segments)
      }
      op += DD;
    }
    soft_barrier();
  }
}

__global__ __launch_bounds__(NTH, 1)
void gru_rec(const float* __restrict__ gi,
             const float* __restrict__ whh0, const float* __restrict__ bhh0,
             const float* __restrict__ wih1, const float* __restrict__ whh1, const float* __restrict__ bih1, const float* __restrict__ bhh1,
             const float* __restrict__ wih2, const float* __restrict__ whh2, const float* __restrict__ bih2, const float* __restrict__ bhh2,
             const float* __restrict__ wih3, const float* __restrict__ whh3, const float* __restrict__ bih3, const float* __restrict__ bhh3,
             const float* __restrict__ wih4, const float* __restrict__ whh4, const float* __restrict__ bih4, const float* __restrict__ bhh4,
             const float* __restrict__ out_w, const float* __restrict__ out_b,
             float* __restrict__ out)
{
  __shared__ __align__(16) u16 FRu[FRTOT2];
  const int tid = threadIdx.x;
  const int w = tid >> 6, lane = tid & 63;
  const int b0 = blockIdx.x * BB;

  for (int i = tid; i < FRTOT2; i += NTH) FRu[i] = 0;
  __syncthreads();

  if (w == 0)
    wave_l0(whh0, bhh0, gi,  0, FRu, b0, lane);
  else if (w == 1)
    wave_l0(whh0, bhh0, gi, 16, FRu, b0, lane);
  else if (w == 2)
    wave_mid<32,16>(wih1,whh1,bih1,bhh1,  0, PH0, PH1, 1, 512, FRu, b0, lane);
  else if (w == 4)
    wave_mid<16, 8>(wih2,whh2,bih2,bhh2,  0, PH1, PH2, 2, 513, FRu, b0, lane);
  else if (w == 5)
    wave_mid< 8,16>(wih3,whh3,bih3,bhh3,  0, PH2, PH3, 3, 514, FRu, b0, lane);
  else if (w == 3)
    wave_mid<16,32>(wih4,whh4,bih4,bhh4,  0, PH3, PH4, 4, 515, FRu, b0, lane);
  else if (w == 6)
    wave_mid<16,32>(wih4,whh4,bih4,bhh4, 16, PH3, PH4, 4, 515, FRu, b0, lane);
  else
    wave_out2(out_w, out_b, FRu, out, b0, lane);
}

// =====================================================================
// Fallback: round-3 kernel (used only if ws_size is too small for gi0)
// =====================================================================
__device__ __forceinline__ void write_x(u16* FRu, int par, int w, int lane, float v)
{
  const int d = lane;
  const int chunk = d >> 5, kb = (d >> 3) & 3, e = d & 7;
  u16 h = f2bf(v);
  u16 l2 = f2bf(v - bf2f(h));
  u16* p = FRu + par*PSTRIDE + XIN0 + chunk*CHUNK + kb*256 + w*8 + e;
  p[0] = h; p[128] = l2;
}

template<int DIN, int DH, int NXC>
__device__ __forceinline__ void wave_gru_fb(
    const float* __restrict__ Wih, const float* __restrict__ Whh,
    const float* __restrict__ bih, const float* __restrict__ bhh,
    int jbase, int xc, int hc, int s0, int s1,
    u16* FRu, float* OST,
    const float* __restrict__ X, const float* __restrict__ Mm, const float* __restrict__ Ll,
    float* __restrict__ out, int b0, int w, int lane)
{
  const int nrow = (DH - jbase) < 16 ? (DH - jbase) : 16;
  s16x8 Axh[3][NXC], Axl[3][NXC], Ahh[3], Ahl[3];
#pragma unroll
  for (int g = 0; g < 3; ++g) {
#pragma unroll
    for (int c = 0; c < NXC; ++c)
      load_wfrag(Wih, g*DH + jbase, nrow, DIN, c*32, lane, Axh[g][c], Axl[g][c]);
    load_wfrag(Whh, g*DH + jbase, nrow, DH, 0, lane, Ahh[g], Ahl[g]);
  }
  f32x4 cR, cZ, cNi, cNh;
  {
    const int q = lane >> 4;
#pragma unroll
    for (int i = 0; i < 4; ++i) {
      int lr = q*4 + i;
      int j = jbase + lr;
      bool jr = lr < nrow;
      cR[i]  = jr ? bih[j] + bhh[j] : 0.f;
      cZ[i]  = jr ? bih[DH+j] + bhh[DH+j] : 0.f;
      cNi[i] = jr ? bih[2*DH+j] : 0.f;
      cNh[i] = jr ? bhh[2*DH+j] : 0.f;
    }
  }
  float hprev[4] = {0.f, 0.f, 0.f, 0.f};

  const size_t gbase = ((size_t)(b0 + w))*((size_t)NT*DD) + lane;
  float rx = X[gbase], rm = Mm[gbase], rl = Ll[gbase];
  write_x(FRu, 1, w, lane, rx*rm + rl*(1.0f - rm));
  rx = X[gbase + DD]; rm = Mm[gbase + DD]; rl = Ll[gbase + DD];
  __syncthreads();

  for (int s = 0; s < NSTEP_FB; ++s) {
    const int par = s & 1, rp = par ^ 1;
    float nx = 0.f, nm = 0.f, nl = 0.f;
    if (s <= 509) {
      size_t g = gbase + (size_t)(s+2)*DD;
      nx = X[g]; nm = Mm[g]; nl = Ll[g];
    }
    f32x4 aR = cR, aZ = cZ, aNi = cNi, aNh = cNh;
    const bool run = (s >= s0) && (s <= s1);
    if (run) {
      const u16* RB = FRu + rp*PSTRIDE;
      s16x8 bh_, bl_;
#pragma unroll
      for (int c = 0; c < NXC; ++c) {
        read_b(RB + xc + c*CHUNK, lane, bh_, bl_);
        aR  = MFMA16(Axh[0][c], bh_, aR);  aR  = MFMA16(Axh[0][c], bl_, aR);  aR  = MFMA16(Axl[0][c], bh_, aR);
        aZ  = MFMA16(Axh[1][c], bh_, aZ);  aZ  = MFMA16(Axh[1][c], bl_, aZ);  aZ  = MFMA16(Axl[1][c], bh_, aZ);
        aNi = MFMA16(Axh[2][c], bh_, aNi); aNi = MFMA16(Axh[2][c], bl_, aNi); aNi = MFMA16(Axl[2][c], bh_, aNi);
      }
      read_b(RB + hc, lane, bh_, bl_);
      aR  = MFMA16(Ahh[0], bh_, aR);  aR  = MFMA16(Ahh[0], bl_, aR);  aR  = MFMA16(Ahl[0], bh_, aR);
      aZ  = MFMA16(Ahh[1], bh_, aZ);  aZ  = MFMA16(Ahh[1], bl_, aZ);  aZ  = MFMA16(Ahl[1], bh_, aZ);
      aNh = MFMA16(Ahh[2], bh_, aNh); aNh = MFMA16(Ahh[2], bl_, aNh); aNh = MFMA16(Ahl[2], bh_, aNh);
    }
    __syncthreads();

    if (run)
      combine_write(aR, aZ, aNi, aNh, hprev, FRu + par*PSTRIDE + hc, jbase, nrow, lane);
    if (s >= 5)
      out[((size_t)(b0 + w)*NT + (s-5))*DD + lane] = OST[w*65 + lane];
    if (s <= 510) write_x(FRu, par, w, lane, rx*rm + rl*(1.0f - rm));
    rx = nx; rm = nm; rl = nl;
    __syncthreads();
  }
}

__device__ __forceinline__ void wave_out_fb(
    const float* __restrict__ OW, const float* __restrict__ OBb,
    u16* FRu, float* OST,
    const float* __restrict__ X, const float* __restrict__ Mm, const float* __restrict__ Ll,
    float* __restrict__ out, int b0, int w, int lane)
{
  s16x8 Oh[4], Ol[4];
  f32x4 cO[4];
#pragma unroll
  for (int t4 = 0; t4 < 4; ++t4) {
    load_wfrag(OW, t4*16, 16, 32, 0, lane, Oh[t4], Ol[t4]);
#pragma unroll
    for (int i = 0; i < 4; ++i) cO[t4][i] = OBb[t4*16 + (lane>>4)*4 + i];
  }
  const size_t gbase = ((size_t)(b0 + w))*((size_t)NT*DD) + lane;
  float rx = X[gbase], rm = Mm[gbase], rl = Ll[gbase];
  write_x(FRu, 1, w, lane, rx*rm + rl*(1.0f - rm));
  rx = X[gbase + DD]; rm = Mm[gbase + DD]; rl = Ll[gbase + DD];
  __syncthreads();

  for (int s = 0; s < NSTEP_FB; ++s) {
    const int par = s & 1, rp = par ^ 1;
    float nx = 0.f, nm = 0.f, nl = 0.f;
    if (s <= 509) { size_t g = gbase + (size_t)(s+2)*DD; nx = X[g]; nm = Mm[g]; nl = Ll[g]; }
    if (s >= 5) {
      s16x8 bh_, bl_;
      read_b(FRu + rp*PSTRIDE + H4C, lane, bh_, bl_);
      const int bb = lane & 15, q = lane >> 4;
#pragma unroll
      for (int t4 = 0; t4 < 4; ++t4) {
        f32x4 a_ = cO[t4];
        a_ = MFMA16(Oh[t4], bh_, a_); a_ = MFMA16(Oh[t4], bl_, a_); a_ = MFMA16(Ol[t4], bh_, a_);
        if (bb < 8) {
#pragma unroll
          for (int i = 0; i < 4; ++i) OST[bb*65 + t4*16 + q*4 + i] = a_[i];
        }
      }
    }
    __syncthreads();
    if (s >= 5)
      out[((size_t)(b0 + w)*NT + (s-5))*DD + lane] = OST[w*65 + lane];
    if (s <= 510) write_x(FRu, par, w, lane, rx*rm + rl*(1.0f - rm));
    rx = nx; rm = nm; rl = nl;
    __syncthreads();
  }
}

__global__ __launch_bounds__(NTH, 1)
void gru_mfma(const float* __restrict__ X, const float* __restrict__ M, const float* __restrict__ L,
              const float* __restrict__ wih0, const float* __restrict__ whh0, const float* __restrict__ bih0, const float* __restrict__ bhh0,
              const float* __restrict__ wih1, const float* __restrict__ whh1, const float* __restrict__ bih1, const float* __restrict__ bhh1,
              const float* __restrict__ wih2, const float* __restrict__ whh2, const float* __restrict__ bih2, const float* __restrict__ bhh2,
              const float* __restrict__ wih3, const float* __restrict__ whh3, const float* __restrict__ bih3, const float* __restrict__ bhh3,
              const float* __restrict__ wih4, const float* __restrict__ whh4, const float* __restrict__ bih4, const float* __restrict__ bhh4,
              const float* __restrict__ out_w, const float* __restrict__ out_b,
              float* __restrict__ out)
{
  __shared__ __align__(16) u16 FRu[FRTOT];
  __shared__ float OST[8*65];
  const int tid = threadIdx.x;
  const int w = tid >> 6, lane = tid & 63;
  const int b0 = blockIdx.x * BB;

  for (int i = tid; i < FRTOT; i += NTH) FRu[i] = 0;
  for (int i = tid; i < 8*65; i += NTH) OST[i] = 0.f;
  __syncthreads();

  if (w == 0)
    wave_gru_fb<64,32,2>(wih0,whh0,bih0,bhh0,  0, XIN0, H0C, 0, 511, FRu, OST, X,M,L, out, b0, w, lane);
  else if (w == 1)
    wave_gru_fb<64,32,2>(wih0,whh0,bih0,bhh0, 16, XIN0, H0C, 0, 511, FRu, OST, X,M,L, out, b0, w, lane);
  else if (w == 2)
    wave_gru_fb<32,16,1>(wih1,whh1,bih1,bhh1,  0, H0C,  H1C, 1, 512, FRu, OST, X,M,L, out, b0, w, lane);
  else if (w == 4)
    wave_gru_fb<16, 8,1>(wih2,whh2,bih2,bhh2,  0, H1C,  H2C, 2, 513, FRu, OST, X,M,L, out, b0, w, lane);
  else if (w == 5)
    wave_gru_fb< 8,16,1>(wih3,whh3,bih3,bhh3,  0, H2C,  H3C, 3, 514, FRu, OST, X,M,L, out, b0, w, lane);
  else if (w == 3)
    wave_gru_fb<16,32,1>(wih4,whh4,bih4,bhh4,  0, H3C,  H4C, 4, 515, FRu, OST, X,M,L, out, b0, w, lane);
  else if (w == 6)
    wave_gru_fb<16,32,1>(wih4,whh4,bih4,bhh4, 16, H3C,  H4C, 4, 515, FRu, OST, X,M,L, out, b0, w, lane);
  else
    wave_out_fb(out_w, out_b, FRu, OST, X,M,L, out, b0, w, lane);
}

extern "C" void kernel_launch(void* const* d_in, const int* in_sizes, int n_in,
                              void* d_out, int out_size, void* d_ws, size_t ws_size,
                              hipStream_t stream)
{
  const float* X  = (const float*)d_in[0];
  const float* M  = (const float*)d_in[1];
  const float* L  = (const float*)d_in[2];
  const float* wp[20];
  for (int i = 0; i < 20; ++i) wp[i] = (const float*)d_in[3 + i];
  const float* ow = (const float*)d_in[23];
  const float* ob = (const float*)d_in[24];
  float* out = (float*)d_out;

  const size_t gi_bytes = (size_t)2048 * NT * 96 * sizeof(float);  // 402,653,184
  if (ws_size >= gi_bytes) {
    float* gi = (float*)d_ws;
    gi0_gemm<<<dim3(2048*4), dim3(256), 0, stream>>>(X, M, L, wp[0], wp[2], wp[3], gi);
    gru_rec<<<dim3(2048 / BB), dim3(NTH), 0, stream>>>(
        gi, wp[1], wp[3],
        wp[4], wp[5], wp[6], wp[7],
        wp[8], wp[9], wp[10], wp[11],
        wp[12], wp[13], wp[14], wp[15],
        wp[16], wp[17], wp[18], wp[19],
        ow, ob, out);
  } else {
    gru_mfma<<<dim3(2048 / BB), dim3(NTH), 0, stream>>>(
        X, M, L,
        wp[0], wp[1], wp[2], wp[3],
        wp[4], wp[5], wp[6], wp[7],
        wp[8], wp[9], wp[10], wp[11],
        wp[12], wp[13], wp[14], wp[15],
        wp[16], wp[17], wp[18], wp[19],
        ow, ob, out);
  }
}